// Round 6
// baseline (403.577 us; speedup 1.0000x reference)
//
#include <hip/hip_runtime.h>
#include <math.h>

// CapsuleLayer dynamic routing — round 6.
// B=64, N=4096, I=8, C=32, D=16, 3 routing iterations.
//
// Round-5 post-mortem: occupancy 10% (grid 512, VGPR 132), W re-fetched per
// XCD (FETCH 67MB). Fixes: grid 1024 (256 nb x 4 bq) with XCD swizzle so all
// bq replicas of an nb share blockIdx%8 (W slice 4MB/XCD -> L2-resident);
// softmax reduction now 4 DPP adds + 2 shuffles (full-wave sum = 2*denom);
// converts fused into one launch.
//
// Layouts in ws:
//   Wh  f16 [n][k=0..7][l=0..63][8 i]  (32 MiB)  unit(n,k,l) = cj=l*8+k
//   xh  f16 [n][b][8 i]                (4 MiB)
//   partial f16 [nb=256][bq=4][b=16][512 cj]  (16 MiB)
//   OcumG f16 [b=64][512 cj]           (64 KiB)

typedef __fp16 h2 __attribute__((ext_vector_type(2)));

#define DPP_ADD(v, ctrl) ((v) + __int_as_float(__builtin_amdgcn_mov_dpp(__float_as_int(v), (ctrl), 0xf, 0xf, true)))
// quad_perm[1,0,3,2]=0xB1 (xor1), quad_perm[2,3,0,1]=0x4E (xor2),
// row_ror:4=0x124, row_ror:8=0x128

__device__ __forceinline__ float fdot2(h2 a, h2 b, float c) {
    return __builtin_amdgcn_fdot2(a, b, c, false);
}

// ---- conversion (one launch: blocks 0..4095 -> W, 4096..5119 -> x) --------

__global__ __launch_bounds__(256) void convert_all(const float* __restrict__ W,
                                                   const float* __restrict__ x,
                                                   ushort* __restrict__ Wh,
                                                   ushort* __restrict__ xh) {
    const int t = threadIdx.x;
    if (blockIdx.x < 4096) {
        const int n = blockIdx.x;
        const int cj0 = 2 * t;                       // even
        const int c = cj0 >> 4, j0 = cj0 & 15;
        const float* src = W + (size_t)c * 524288 + (size_t)n * 128 + j0 * 8;
        float4 a = *reinterpret_cast<const float4*>(src);
        float4 b = *reinterpret_cast<const float4*>(src + 4);
        float4 cc = *reinterpret_cast<const float4*>(src + 8);
        float4 d = *reinterpret_cast<const float4*>(src + 12);
        __fp16 qa[8] = {(__fp16)a.x, (__fp16)a.y, (__fp16)a.z, (__fp16)a.w,
                        (__fp16)b.x, (__fp16)b.y, (__fp16)b.z, (__fp16)b.w};
        __fp16 qb[8] = {(__fp16)cc.x, (__fp16)cc.y, (__fp16)cc.z, (__fp16)cc.w,
                        (__fp16)d.x, (__fp16)d.y, (__fp16)d.z, (__fp16)d.w};
        uint4* dst = reinterpret_cast<uint4*>(Wh);
        const int l = t >> 2, k0 = cj0 & 7;          // cj0 = l*8 + k0
        dst[((size_t)n * 8 + k0) * 64 + l] = *reinterpret_cast<uint4*>(qa);
        dst[((size_t)n * 8 + k0 + 1) * 64 + l] = *reinterpret_cast<uint4*>(qb);
    } else {
        const int gid = (blockIdx.x - 4096) * 256 + t;    // 0..262143
        const int b = gid >> 12, n = gid & 4095;
        const float* src = x + (size_t)b * 32768 + (size_t)n * 8;
        float4 a = *reinterpret_cast<const float4*>(src);
        float4 c = *reinterpret_cast<const float4*>(src + 4);
        __fp16 q[8] = {(__fp16)a.x, (__fp16)a.y, (__fp16)a.z, (__fp16)a.w,
                       (__fp16)c.x, (__fp16)c.y, (__fp16)c.z, (__fp16)c.w};
        reinterpret_cast<uint4*>(xh)[(size_t)n * 64 + b] = *reinterpret_cast<uint4*>(q);
    }
}

// ---- main fused routing pass ----------------------------------------------

__device__ __forceinline__ void loadfrag(uint4 wv[8], const uint4* __restrict__ Whu,
                                         int n, int lane) {
    #pragma unroll
    for (int k = 0; k < 8; ++k) wv[k] = Whu[((size_t)n * 8 + k) * 64 + lane];
}

template <int UNI>
__global__ __launch_bounds__(256, 3) void fused_pass(const ushort* __restrict__ Wh,
                                                     const ushort* __restrict__ xh,
                                                     const ushort* __restrict__ OcumG,
                                                     uint4* __restrict__ partialU) {
    // XCD swizzle: all 4 bq replicas of an nb share blockIdx%8 -> same XCD.
    const int sx = blockIdx.x & 7, j = blockIdx.x >> 3;      // j: 0..127
    const int nb = ((j & 31) << 3) | sx;                     // 0..255
    const int bq = j >> 5;                                   // 0..3
    const int n0 = nb * 16, b0 = bq * 16;
    const int t = threadIdx.x, lane = t & 63, w = t >> 6;

    __shared__ __align__(16) uint4 smem[2048];               // 32 KB
    uint4* xlsu = smem;                                      // 256: [nl 16][bl 16]
    uint4* ocmu = smem + 256;                                // 1024: [bl 16][l 64]

    const uint4* xhu = reinterpret_cast<const uint4*>(xh);
    if (t < 256) {
        int nl = t >> 4, bl = t & 15;
        xlsu[t] = xhu[(size_t)(n0 + nl) * 64 + b0 + bl];
    }
    if (!UNI) {
        const uint4* ocg = reinterpret_cast<const uint4*>(OcumG);
        for (int u = t; u < 1024; u += 256) {
            int bl = u >> 6, l = u & 63;
            ocmu[u] = ocg[(size_t)(b0 + bl) * 64 + l];
        }
    }
    __syncthreads();

    h2 acc[16][4];
    #pragma unroll
    for (int b = 0; b < 16; ++b)
        #pragma unroll
        for (int jp = 0; jp < 4; ++jp) acc[b][jp] = (h2)(__fp16)0.f;

    const uint4* Whu = reinterpret_cast<const uint4*>(Wh);
    const int nA = n0 + w * 4;                               // wave owns 4 n

    uint4 wva[8], wvb[8];
    loadfrag(wva, Whu, nA, lane);

    #pragma unroll 1
    for (int s = 0; s < 4; ++s) {
        if (s + 1 < 4) loadfrag((s & 1) ? wva : wvb, Whu, nA + s + 1, lane);
        const uint4* wv = (s & 1) ? wvb : wva;
        const h2* wh = reinterpret_cast<const h2*>(wv);
        const uint4* xrow = xlsu + (w * 4 + s) * 16;
        #pragma unroll
        for (int b = 0; b < 16; ++b) {
            uint4 xv = xrow[b];                              // wave-uniform: broadcast
            const h2* xp = reinterpret_cast<const h2*>(&xv);
            float h[8];
            #pragma unroll
            for (int k = 0; k < 8; ++k) {
                float sacc = fdot2(wh[k * 4 + 0], xp[0], 0.f);
                sacc = fdot2(wh[k * 4 + 1], xp[1], sacc);
                sacc = fdot2(wh[k * 4 + 2], xp[2], sacc);
                h[k] = fdot2(wh[k * 4 + 3], xp[3], sacc);
            }
            h2 hh[4];
            #pragma unroll
            for (int jp = 0; jp < 4; ++jp)
                hh[jp] = __builtin_amdgcn_cvt_pkrtz(h[2 * jp], h[2 * jp + 1]);

            float ccf;
            if (UNI) {
                ccf = 0.03125f;
            } else {
                uint4 ov = ocmu[b * 64 + lane];
                const h2* op = reinterpret_cast<const h2*>(&ov);
                float p = fdot2(op[0], hh[0], 0.f);
                p = fdot2(op[1], hh[1], p);
                p = fdot2(op[2], hh[2], p);
                p = fdot2(op[3], hh[3], p);
                p = DPP_ADD(p, 0xB1);              // pair-sum: full logit, dup in pair
                float e = __expf(p);               // |p| small: no max-sub needed
                // full 64-lane sum = 2 * denom (each c duplicated in a pair)
                float sm = DPP_ADD(e, 0xB1);       // quad partial
                sm = DPP_ADD(sm, 0x4E);            // quad sum
                sm = DPP_ADD(sm, 0x124);           // + row_ror:4
                sm = DPP_ADD(sm, 0x128);           // + row_ror:8 -> 16-lane row sum
                sm += __shfl_xor(sm, 16, 64);
                sm += __shfl_xor(sm, 32, 64);      // 64-lane sum
                ccf = (e + e) * __builtin_amdgcn_rcpf(sm);
            }
            h2 cs;
            cs.x = (__fp16)ccf;
            cs.y = cs.x;
            #pragma unroll
            for (int jp = 0; jp < 4; ++jp) acc[b][jp] = hh[jp] * cs + acc[b][jp];
        }
    }

    // ---- epilogue: cross-wave reduce in LDS, 2 phases of 8 b ----
    const size_t pbase = (size_t)(nb * 4 + bq) * 1024;
    #pragma unroll
    for (int ph = 0; ph < 2; ++ph) {
        __syncthreads();
        #pragma unroll
        for (int b8 = 0; b8 < 8; ++b8)
            smem[w * 512 + b8 * 64 + lane] = *reinterpret_cast<uint4*>(&acc[ph * 8 + b8][0]);
        __syncthreads();
        for (int o = t; o < 512; o += 256) {                 // o = b8*64 + l
            float sv[8] = {0.f, 0.f, 0.f, 0.f, 0.f, 0.f, 0.f, 0.f};
            #pragma unroll
            for (int ww = 0; ww < 4; ++ww) {
                uint4 v = smem[ww * 512 + o];
                const h2* vh = reinterpret_cast<const h2*>(&v);
                #pragma unroll
                for (int q = 0; q < 4; ++q) {
                    sv[2 * q] += (float)vh[q].x;
                    sv[2 * q + 1] += (float)vh[q].y;
                }
            }
            h2 pk[4];
            #pragma unroll
            for (int q = 0; q < 4; ++q)
                pk[q] = __builtin_amdgcn_cvt_pkrtz(sv[2 * q], sv[2 * q + 1]);
            partialU[pbase + (size_t)ph * 512 + o] = *reinterpret_cast<uint4*>(pk);
        }
    }
}

// ---- final reduce + squash + Ocum update ----------------------------------

__global__ __launch_bounds__(256) void reduce_squash(const unsigned* __restrict__ partial32,
                                                     ushort* __restrict__ OcumG,
                                                     float* __restrict__ out,
                                                     int passIdx) {
    const int tid = blockIdx.x * 256 + threadIdx.x;          // 0..16383
    const int b = tid >> 8, cjp = tid & 255;
    const int base = (b >> 4) * 4096 + (b & 15) * 256 + cjp;
    float sx = 0.f, sy = 0.f;
    for (int nb = 0; nb < 256; ++nb) {
        union { unsigned u; h2 h; } v;
        v.u = partial32[base + nb * 16384];
        sx += (float)v.h.x;
        sy += (float)v.h.y;
    }
    float s2 = sx * sx + sy * sy;                            // 16 j live in 8 lanes
    s2 += __shfl_xor(s2, 1, 64);
    s2 += __shfl_xor(s2, 2, 64);
    s2 += __shfl_xor(s2, 4, 64);
    float scale = (s2 / (1.f + s2)) / sqrtf(s2 + 1e-7f);
    float o0 = scale * sx, o1 = scale * sy;

    unsigned* ocp = reinterpret_cast<unsigned*>(OcumG) + b * 256 + cjp;
    float a0 = o0, a1 = o1;
    if (passIdx) {
        union { unsigned u; h2 h; } old;
        old.u = *ocp;
        a0 += (float)old.h.x;
        a1 += (float)old.h.y;
    }
    union { h2 h; unsigned u; } nw;
    nw.h = __builtin_amdgcn_cvt_pkrtz(a0, a1);
    *ocp = nw.u;

    if (passIdx == 2) {
        out[b * 512 + cjp * 2] = o0;
        out[b * 512 + cjp * 2 + 1] = o1;
    }
}

// ---- host ------------------------------------------------------------------

extern "C" void kernel_launch(void* const* d_in, const int* in_sizes, int n_in,
                              void* d_out, int out_size, void* d_ws, size_t ws_size,
                              hipStream_t stream) {
    const float* x = (const float*)d_in[0];
    const float* W = (const float*)d_in[1];
    float* out = (float*)d_out;

    char* ws = (char*)d_ws;
    ushort* Wh = (ushort*)ws;                                   // 32 MiB
    ushort* xh = (ushort*)(ws + (size_t)32 * 1024 * 1024);      // 4 MiB
    uint4* partialU = (uint4*)(ws + (size_t)36 * 1024 * 1024);  // 16 MiB
    ushort* OcumG = (ushort*)(ws + (size_t)52 * 1024 * 1024);   // 64 KiB

    convert_all<<<5120, 256, 0, stream>>>(W, x, Wh, xh);

    for (int pass = 0; pass < 3; ++pass) {
        if (pass == 0)
            fused_pass<1><<<1024, 256, 0, stream>>>(Wh, xh, OcumG, partialU);
        else
            fused_pass<0><<<1024, 256, 0, stream>>>(Wh, xh, OcumG, partialU);
        reduce_squash<<<64, 256, 0, stream>>>((const unsigned*)partialU, OcumG, out, pass);
    }
}

// Round 7
// 234.622 us; speedup vs baseline: 1.7201x; 1.7201x over previous
//
#include <hip/hip_runtime.h>
#include <math.h>

// CapsuleLayer dynamic routing — round 7.
// B=64, N=4096, I=8, C=32, D=16, 3 routing iterations.
//
// Round-6 post-mortem: `(s&1) ? wva : wvb` (dynamic pointer select into
// register arrays) forced acc/wv to scratch -> 330 MB spill traffic/pass.
// Round 7: spill-proof structure. Wave tile 8 b x 8 n; ONE constant-indexed
// wv[8] fragment buffer (no ping-pong); acc[8][4] fully unrolled. VGPR ~110
// under launch_bounds(256,4) cap 128 -> 4 blocks/CU, 16 waves/CU.
// Block = 8 b x 32 n (4 waves share the b-set); grid = bg*128 + ntile so all
// 8 b-replicas of an ntile land on one XCD (W slice 4 MB -> L2-resident).
//
// ws: Wh f16 [n][k][l][8i] 32 MiB | xh f16 [n][b][8i] 4 MiB |
//     partial f16 [block 1024][bl 8][l 64][8cj] 8 MiB | OcumG f16 [b][l][8i] 64 KiB

typedef __fp16 h2 __attribute__((ext_vector_type(2)));

#define DPP_ADD(v, ctrl) ((v) + __int_as_float(__builtin_amdgcn_mov_dpp(__float_as_int(v), (ctrl), 0xf, 0xf, true)))
// quad_perm[1,0,3,2]=0xB1 (xor1), quad_perm[2,3,0,1]=0x4E (xor2),
// row_ror:4=0x124, row_ror:8=0x128

__device__ __forceinline__ float fdot2(h2 a, h2 b, float c) {
    return __builtin_amdgcn_fdot2(a, b, c, false);
}

// ---- conversion: blocks 0..4095 -> W, 4096..5119 -> x ----------------------

__global__ __launch_bounds__(256) void convert_all(const float* __restrict__ W,
                                                   const float* __restrict__ x,
                                                   ushort* __restrict__ Wh,
                                                   ushort* __restrict__ xh) {
    const int t = threadIdx.x;
    if (blockIdx.x < 4096) {
        const int n = blockIdx.x;
        const int cj0 = 2 * t;                       // even
        const int c = cj0 >> 4, j0 = cj0 & 15;
        const float* src = W + (size_t)c * 524288 + (size_t)n * 128 + j0 * 8;
        float4 a = *reinterpret_cast<const float4*>(src);
        float4 b = *reinterpret_cast<const float4*>(src + 4);
        float4 cc = *reinterpret_cast<const float4*>(src + 8);
        float4 d = *reinterpret_cast<const float4*>(src + 12);
        __fp16 qa[8] = {(__fp16)a.x, (__fp16)a.y, (__fp16)a.z, (__fp16)a.w,
                        (__fp16)b.x, (__fp16)b.y, (__fp16)b.z, (__fp16)b.w};
        __fp16 qb[8] = {(__fp16)cc.x, (__fp16)cc.y, (__fp16)cc.z, (__fp16)cc.w,
                        (__fp16)d.x, (__fp16)d.y, (__fp16)d.z, (__fp16)d.w};
        uint4* dst = reinterpret_cast<uint4*>(Wh);
        const int l = t >> 2, k0 = cj0 & 7;          // cj0 = l*8 + k0
        dst[((size_t)n * 8 + k0) * 64 + l] = *reinterpret_cast<uint4*>(qa);
        dst[((size_t)n * 8 + k0 + 1) * 64 + l] = *reinterpret_cast<uint4*>(qb);
    } else {
        const int gid = (blockIdx.x - 4096) * 256 + t;    // 0..262143
        const int b = gid >> 12, n = gid & 4095;
        const float* src = x + (size_t)b * 32768 + (size_t)n * 8;
        float4 a = *reinterpret_cast<const float4*>(src);
        float4 c = *reinterpret_cast<const float4*>(src + 4);
        __fp16 q[8] = {(__fp16)a.x, (__fp16)a.y, (__fp16)a.z, (__fp16)a.w,
                       (__fp16)c.x, (__fp16)c.y, (__fp16)c.z, (__fp16)c.w};
        reinterpret_cast<uint4*>(xh)[(size_t)n * 64 + b] = *reinterpret_cast<uint4*>(q);
    }
}

// ---- main fused routing pass ----------------------------------------------

template <int UNI>
__global__ __launch_bounds__(256, 4) void fused_pass(const ushort* __restrict__ Wh,
                                                     const ushort* __restrict__ xh,
                                                     const ushort* __restrict__ OcumG,
                                                     uint4* __restrict__ partialU) {
    const int ntile = blockIdx.x & 127;              // XCD = blockIdx%8 = ntile%8
    const int bg = blockIdx.x >> 7;                  // 0..7
    const int n0 = ntile * 32, b0 = bg * 8;
    const int t = threadIdx.x, lane = t & 63, w = t >> 6;

    __shared__ __align__(16) uint4 smem[2048];       // 32 KB
    uint4* xls = smem;                               // 256: [nl 32][bl 8]
    uint4* ocl = smem + 256;                         // 512: [bl 8][l 64]

    const uint4* xhu = reinterpret_cast<const uint4*>(xh);
    {
        int nl = t >> 3, bl = t & 7;
        xls[t] = xhu[(size_t)(n0 + nl) * 64 + b0 + bl];
    }
    if (!UNI) {
        const uint4* ocg = reinterpret_cast<const uint4*>(OcumG);
        for (int u = t; u < 512; u += 256) {
            int bl = u >> 6, l = u & 63;
            ocl[u] = ocg[(size_t)(b0 + bl) * 64 + l];
        }
    }
    __syncthreads();

    h2 acc[8][4];
    #pragma unroll
    for (int b = 0; b < 8; ++b)
        #pragma unroll
        for (int jp = 0; jp < 4; ++jp) acc[b][jp] = (h2)(__fp16)0.f;

    const uint4* Whu = reinterpret_cast<const uint4*>(Wh);
    const int nA = n0 + w * 8;                       // wave owns 8 n

    #pragma unroll 1
    for (int s = 0; s < 8; ++s) {
        uint4 wv[8];                                 // single buffer, const-indexed
        #pragma unroll
        for (int k = 0; k < 8; ++k)
            wv[k] = Whu[((size_t)(nA + s) * 8 + k) * 64 + lane];
        const h2* wh = reinterpret_cast<const h2*>(wv);
        const uint4* xrow = xls + (w * 8 + s) * 8;

        #pragma unroll
        for (int b = 0; b < 8; ++b) {
            uint4 xv = xrow[b];                      // wave-uniform: LDS broadcast
            const h2* xp = reinterpret_cast<const h2*>(&xv);
            float h[8];
            #pragma unroll
            for (int k = 0; k < 8; ++k) {
                float sacc = fdot2(wh[k * 4 + 0], xp[0], 0.f);
                sacc = fdot2(wh[k * 4 + 1], xp[1], sacc);
                sacc = fdot2(wh[k * 4 + 2], xp[2], sacc);
                h[k] = fdot2(wh[k * 4 + 3], xp[3], sacc);
            }
            h2 hh[4];
            #pragma unroll
            for (int jp = 0; jp < 4; ++jp)
                hh[jp] = __builtin_amdgcn_cvt_pkrtz(h[2 * jp], h[2 * jp + 1]);

            float ccf;
            if (UNI) {
                ccf = 0.03125f;
            } else {
                uint4 ov = ocl[b * 64 + lane];
                const h2* op = reinterpret_cast<const h2*>(&ov);
                float p = fdot2(op[0], hh[0], 0.f);
                p = fdot2(op[1], hh[1], p);
                p = fdot2(op[2], hh[2], p);
                p = fdot2(op[3], hh[3], p);
                p = DPP_ADD(p, 0xB1);                // pair-sum -> full logit per c
                float e = __expf(p);                 // |p| small: no max-sub
                // 64-lane sum = 2 * denominator (each c duplicated in a pair)
                float sm = DPP_ADD(e, 0xB1);
                sm = DPP_ADD(sm, 0x4E);              // quad sum
                sm = DPP_ADD(sm, 0x124);             // + row_ror:4
                sm = DPP_ADD(sm, 0x128);             // + row_ror:8 -> row(16) sum
                sm += __shfl_xor(sm, 16, 64);
                sm += __shfl_xor(sm, 32, 64);        // full 64-lane sum
                ccf = (e + e) * __builtin_amdgcn_rcpf(sm);
            }
            h2 cs;
            cs.x = (__fp16)ccf;
            cs.y = cs.x;
            #pragma unroll
            for (int jp = 0; jp < 4; ++jp) acc[b][jp] = hh[jp] * cs + acc[b][jp];
        }
    }

    // ---- epilogue: cross-wave (same b-set, different n) reduce in LDS ----
    __syncthreads();
    #pragma unroll
    for (int b = 0; b < 8; ++b)
        smem[w * 512 + b * 64 + lane] = *reinterpret_cast<uint4*>(&acc[b][0]);
    __syncthreads();
    for (int o = t; o < 512; o += 256) {             // o = bl*64 + l
        float sv[8] = {0.f, 0.f, 0.f, 0.f, 0.f, 0.f, 0.f, 0.f};
        #pragma unroll
        for (int ww = 0; ww < 4; ++ww) {
            uint4 v = smem[ww * 512 + o];
            const h2* vh = reinterpret_cast<const h2*>(&v);
            #pragma unroll
            for (int q = 0; q < 4; ++q) {
                sv[2 * q] += (float)vh[q].x;
                sv[2 * q + 1] += (float)vh[q].y;
            }
        }
        h2 pk[4];
        #pragma unroll
        for (int q = 0; q < 4; ++q)
            pk[q] = __builtin_amdgcn_cvt_pkrtz(sv[2 * q], sv[2 * q + 1]);
        partialU[(size_t)blockIdx.x * 512 + o] = *reinterpret_cast<uint4*>(pk);
    }
}

// ---- final reduce + squash + Ocum update ----------------------------------
// partial element (b=bg*8+bl, cj): unsigned idx ((bg*128+nt)*512 + bl*64 + l)*4 + (cjp&3)

__global__ __launch_bounds__(256) void reduce_squash(const unsigned* __restrict__ partial32,
                                                     ushort* __restrict__ OcumG,
                                                     float* __restrict__ out,
                                                     int passIdx) {
    const int tid = blockIdx.x * 256 + threadIdx.x;  // 0..16383
    const int b = tid >> 8, cjp = tid & 255;         // cj = 2*cjp
    const int bg = b >> 3, bl = b & 7;
    const unsigned base = ((unsigned)bg * 128 * 512 + (unsigned)bl * 64) * 4 + cjp;
    float sx = 0.f, sy = 0.f;
    for (int nt = 0; nt < 128; ++nt) {
        union { unsigned u; h2 h; } v;
        v.u = partial32[base + nt * 2048];
        sx += (float)v.h.x;
        sy += (float)v.h.y;
    }
    float s2 = sx * sx + sy * sy;                    // 16 j live in 8 lanes
    s2 += __shfl_xor(s2, 1, 64);
    s2 += __shfl_xor(s2, 2, 64);
    s2 += __shfl_xor(s2, 4, 64);
    float scale = (s2 / (1.f + s2)) / sqrtf(s2 + 1e-7f);
    float o0 = scale * sx, o1 = scale * sy;

    unsigned* ocp = reinterpret_cast<unsigned*>(OcumG) + b * 256 + cjp;
    float a0 = o0, a1 = o1;
    if (passIdx) {
        union { unsigned u; h2 h; } old;
        old.u = *ocp;
        a0 += (float)old.h.x;
        a1 += (float)old.h.y;
    }
    union { h2 h; unsigned u; } nw;
    nw.h = __builtin_amdgcn_cvt_pkrtz(a0, a1);
    *ocp = nw.u;

    if (passIdx == 2) {
        out[b * 512 + cjp * 2] = o0;
        out[b * 512 + cjp * 2 + 1] = o1;
    }
}

// ---- host ------------------------------------------------------------------

extern "C" void kernel_launch(void* const* d_in, const int* in_sizes, int n_in,
                              void* d_out, int out_size, void* d_ws, size_t ws_size,
                              hipStream_t stream) {
    const float* x = (const float*)d_in[0];
    const float* W = (const float*)d_in[1];
    float* out = (float*)d_out;

    char* ws = (char*)d_ws;
    ushort* Wh = (ushort*)ws;                                   // 32 MiB
    ushort* xh = (ushort*)(ws + (size_t)32 * 1024 * 1024);      // 4 MiB
    uint4* partialU = (uint4*)(ws + (size_t)36 * 1024 * 1024);  // 8 MiB
    ushort* OcumG = (ushort*)(ws + (size_t)44 * 1024 * 1024);   // 64 KiB

    convert_all<<<5120, 256, 0, stream>>>(W, x, Wh, xh);

    for (int pass = 0; pass < 3; ++pass) {
        if (pass == 0)
            fused_pass<1><<<1024, 256, 0, stream>>>(Wh, xh, OcumG, partialU);
        else
            fused_pass<0><<<1024, 256, 0, stream>>>(Wh, xh, OcumG, partialU);
        reduce_squash<<<64, 256, 0, stream>>>((const unsigned*)partialU, OcumG, out, pass);
    }
}